// Round 11
// baseline (595.071 us; speedup 1.0000x reference)
//
#include <hip/hip_runtime.h>
#include <hip/hip_cooperative_groups.h>

namespace cg = cooperative_groups;

#define KSL 8
#define DIN 128
#define DOUT 128
#define NB 512
#define NT 1024

typedef __attribute__((ext_vector_type(8))) short bf16x8;
typedef __attribute__((ext_vector_type(4))) float f32x4;

// round-to-nearest-even fp32 -> bf16 bits
static __device__ __forceinline__ unsigned int f2b_bits(float f) {
    unsigned int u = __float_as_uint(f);
    return (u + 0x7fffu + ((u >> 16) & 1u)) >> 16;
}

static __device__ __forceinline__ float amax8(float4 a0, float4 a1,
                                              float4 b0, float4 b1) {
    float m = fmaxf(fmaxf(fmaxf(fabsf(a0.x), fabsf(a0.y)), fmaxf(fabsf(a0.z), fabsf(a0.w))),
                    fmaxf(fmaxf(fabsf(a1.x), fabsf(a1.y)), fmaxf(fabsf(a1.z), fabsf(a1.w))));
    m = fmaxf(m, fmaxf(fmaxf(fmaxf(fabsf(b0.x), fabsf(b0.y)), fmaxf(fabsf(b0.z), fabsf(b0.w))),
                       fmaxf(fmaxf(fabsf(b1.x), fabsf(b1.y)), fmaxf(fabsf(b1.z), fabsf(b1.w)))));
    return m;
}

static __device__ __forceinline__ unsigned int pack4(float4 v, float inv) {
    int q0 = __float2int_rn(v.x * inv), q1 = __float2int_rn(v.y * inv);
    int q2 = __float2int_rn(v.z * inv), q3 = __float2int_rn(v.w * inv);
    return (q0 & 0xff) | ((q1 & 0xff) << 8) | ((q2 & 0xff) << 16) |
           ((unsigned)(q3 & 0xff) << 24);
}

static __device__ __forceinline__ void quant_store(
        char* __restrict__ xq, float* __restrict__ scales, int w, int lane,
        float4 a0, float4 a1, float4 b0, float4 b1, float m) {
    float inv = (m > 0.f) ? 127.f / m : 0.f;
    uint4 o;
    o.x = pack4(a0, inv);
    o.y = pack4(a1, inv);
    o.z = pack4(b0, inv);
    o.w = pack4(b1, inv);
    *(uint4*)(xq + (size_t)w * 1024 + lane * 16) = o;
    if (lane == 0) scales[w] = m * (1.f / 127.f);
}

static __device__ __forceinline__ void fill_edge(
        int s, int d, const float* __restrict__ dinv,
        const float* __restrict__ scales, const int* __restrict__ off,
        int* __restrict__ cursor, int2* __restrict__ csr) {
    int pos = atomicAdd(&cursor[d], 1);
    csr[off[d] + pos] = make_int2(s, __float_as_int(dinv[s] * dinv[d] * scales[s]));
}

// ---------------- ONE cooperative dispatch for the whole prep chain ----------
// 512 blocks x 1024 thr (2 blocks/CU co-resident, 32 waves/CU). Quant phase
// batches 2 nodes per wave iteration: 8 independent 16B loads in flight
// (r10 had 4 at 16 waves/CU -> 0.9 TB/s latency-bound; 4x concurrency).
__global__ __launch_bounds__(NT, 8) void build_all(
        const float* __restrict__ x, char* __restrict__ xq,
        float* __restrict__ scales, int N,
        const int* __restrict__ src, const int* __restrict__ dst, int E,
        int* __restrict__ deg, int* __restrict__ cursor, int* __restrict__ off,
        float* __restrict__ dinv, int* __restrict__ blockSums,
        int2* __restrict__ csr) {
    cg::grid_group grid = cg::this_grid();
    __shared__ int sbuf[NT];

    int b = blockIdx.x, t = threadIdx.x;
    int tid0 = b * NT + t;
    int gsz = gridDim.x * NT;
    int nb = gridDim.x;

    // ---- phase 0: zero deg & cursor ----
    for (int i = tid0; i < N; i += gsz) { deg[i] = 0; cursor[i] = 0; }
    grid.sync();

    // ---- phase 1a: quantize, 2 nodes per wave iteration ----
    {
        int nwaves = gsz >> 6;
        int wv = tid0 >> 6, lane = tid0 & 63;
        int ks = lane >> 3, chunk = lane & 7;
        int g = chunk >> 1, ktb = (chunk & 1) * 2;
        size_t eofs = (size_t)ks * DIN + ktb * 32 + g * 8;  // fp32 offset in node
        for (int w0 = wv * 2; w0 < N; w0 += nwaves * 2) {
            int w1 = (w0 + 1 < N) ? w0 + 1 : w0;
            const float* p0 = x + (size_t)w0 * (KSL * DIN) + eofs;
            const float* p1 = x + (size_t)w1 * (KSL * DIN) + eofs;
            float4 a0 = ((const float4*)p0)[0];
            float4 a1 = ((const float4*)p0)[1];
            float4 b0 = ((const float4*)(p0 + 32))[0];
            float4 b1 = ((const float4*)(p0 + 32))[1];
            float4 c0 = ((const float4*)p1)[0];
            float4 c1 = ((const float4*)p1)[1];
            float4 d0 = ((const float4*)(p1 + 32))[0];
            float4 d1 = ((const float4*)(p1 + 32))[1];
            float m0 = amax8(a0, a1, b0, b1);
            float m1 = amax8(c0, c1, d0, d1);
            #pragma unroll
            for (int s = 32; s > 0; s >>= 1) {
                m0 = fmaxf(m0, __shfl_xor(m0, s));
                m1 = fmaxf(m1, __shfl_xor(m1, s));
            }
            quant_store(xq, scales, w0, lane, a0, a1, b0, b1, m0);
            quant_store(xq, scales, w1, lane, c0, c1, d0, d1, m1);
        }
    }
    // ---- phase 1b: degree count (int4 edge loads, grid-stride) ----
    int e4 = E >> 2;
    for (int i = tid0; i < e4; i += gsz) {
        int4 d = ((const int4*)dst)[i];
        atomicAdd(&deg[d.x], 1);
        atomicAdd(&deg[d.y], 1);
        atomicAdd(&deg[d.z], 1);
        atomicAdd(&deg[d.w], 1);
    }
    for (int i = e4 * 4 + tid0; i < E; i += gsz) atomicAdd(&deg[dst[i]], 1);
    grid.sync();

    // ---- phase 2: per-block run sums + block-local prefix (kept in regs) ----
    int chunkN = (N + nb - 1) / nb;             // nodes per block
    int r = (chunkN + NT - 1) / NT;             // nodes per thread (serial run)
    int i0 = b * chunkN + t * r;
    int iend = min(b * chunkN + chunkN, N);
    int s = 0;
    for (int j = 0; j < r; j++) {
        int i = i0 + j;
        if (i < iend) s += deg[i];
    }
    sbuf[t] = s;
    __syncthreads();
    for (int st = 1; st < NT; st <<= 1) {
        int u = (t >= st) ? sbuf[t - st] : 0;
        __syncthreads();
        sbuf[t] += u;
        __syncthreads();
    }
    int myExcl = sbuf[t] - s;                   // exclusive prefix within block
    if (t == NT - 1) blockSums[b] = sbuf[t];    // block total
    grid.sync();

    // ---- phase 3: block 0 scans the nb block totals ----
    if (b == 0) {
        int v = (t < nb) ? blockSums[t] : 0;
        sbuf[t] = v;
        __syncthreads();
        for (int st = 1; st < NT; st <<= 1) {
            int u = (t >= st) ? sbuf[t - st] : 0;
            __syncthreads();
            sbuf[t] += u;
            __syncthreads();
        }
        if (t < nb) blockSums[t] = sbuf[t] - v; // exclusive base per block
        if (t == nb - 1) off[N] = sbuf[t];      // grand total
    }
    grid.sync();

    // ---- phase 4: write offsets + dinv ----
    {
        int run = blockSums[b] + myExcl;
        for (int j = 0; j < r; j++) {
            int i = i0 + j;
            if (i < iend) {
                int d = deg[i];
                off[i] = run;
                run += d;
                dinv[i] = rsqrtf((float)(d + 1));   // +1 self-loop
            }
        }
    }
    grid.sync();

    // ---- phase 5: fill csr (scale folded into weight) ----
    for (int i = tid0; i < e4; i += gsz) {
        int4 s4 = ((const int4*)src)[i];
        int4 d4 = ((const int4*)dst)[i];
        fill_edge(s4.x, d4.x, dinv, scales, off, cursor, csr);
        fill_edge(s4.y, d4.y, dinv, scales, off, cursor, csr);
        fill_edge(s4.z, d4.z, dinv, scales, off, cursor, csr);
        fill_edge(s4.w, d4.w, dinv, scales, off, cursor, csr);
    }
    for (int i = e4 * 4 + tid0; i < E; i += gsz)
        fill_edge(src[i], dst[i], dinv, scales, off, cursor, csr);
}

// ---------------- fallback (r9 path) kernels ----------------
__global__ __launch_bounds__(256) void quant_deg_fb(
        const float* __restrict__ x, char* __restrict__ xq,
        float* __restrict__ scales, int N,
        const int* __restrict__ dst, int E, int* __restrict__ deg) {
    long long tid = (long long)blockIdx.x * blockDim.x + threadIdx.x;
    int e4 = E >> 2;
    if (tid < e4) {
        int4 d = ((const int4*)dst)[tid];
        atomicAdd(&deg[d.x], 1);
        atomicAdd(&deg[d.y], 1);
        atomicAdd(&deg[d.z], 1);
        atomicAdd(&deg[d.w], 1);
    }
    if (tid < (E & 3)) atomicAdd(&deg[dst[e4 * 4 + tid]], 1);
    int w = (int)(tid >> 6);
    int lane = (int)(tid & 63);
    if (w < N) {
        int ks = lane >> 3, chunk = lane & 7;
        int g = chunk >> 1, ktb = (chunk & 1) * 2;
        const float* p0 = x + (size_t)w * (KSL * DIN) + (size_t)ks * DIN + ktb * 32 + g * 8;
        float4 a0 = ((const float4*)p0)[0];
        float4 a1 = ((const float4*)p0)[1];
        float4 b0 = ((const float4*)(p0 + 32))[0];
        float4 b1 = ((const float4*)(p0 + 32))[1];
        float m = amax8(a0, a1, b0, b1);
        #pragma unroll
        for (int s = 32; s > 0; s >>= 1) m = fmaxf(m, __shfl_xor(m, s));
        quant_store(xq, scales, w, lane, a0, a1, b0, b1, m);
    }
}

__global__ __launch_bounds__(1024) void scan_off_fb(const int* __restrict__ deg, int N,
                                                    int* __restrict__ off,
                                                    float* __restrict__ dinv) {
    __shared__ int part[1024];
    int tid = threadIdx.x;
    int CH = (N + 1023) / 1024;
    int i0 = tid * CH;
    int s = 0;
    for (int j = 0; j < CH; j++) {
        int i = i0 + j;
        if (i < N) {
            int d = deg[i];
            dinv[i] = rsqrtf((float)(d + 1));
            s += d;
        }
    }
    part[tid] = s;
    __syncthreads();
    for (int st = 1; st < 1024; st <<= 1) {
        int t = (tid >= st) ? part[tid - st] : 0;
        __syncthreads();
        part[tid] += t;
        __syncthreads();
    }
    int run = part[tid] - s;
    for (int j = 0; j < CH; j++) {
        int i = i0 + j;
        if (i < N) {
            off[i] = run;
            run += deg[i];
        }
    }
    if (tid == 1023) off[N] = part[1023];
}

__global__ __launch_bounds__(256) void fill_csr_fb(
        const int* __restrict__ src, const int* __restrict__ dst, int E,
        const int* __restrict__ off, int* __restrict__ cursor,
        const float* __restrict__ dinv, const float* __restrict__ scales,
        int2* __restrict__ csr) {
    int i = blockIdx.x * blockDim.x + threadIdx.x;
    int e4 = E >> 2;
    if (i < e4) {
        int4 s4 = ((const int4*)src)[i];
        int4 d4 = ((const int4*)dst)[i];
        fill_edge(s4.x, d4.x, dinv, scales, off, cursor, csr);
        fill_edge(s4.y, d4.y, dinv, scales, off, cursor, csr);
        fill_edge(s4.z, d4.z, dinv, scales, off, cursor, csr);
        fill_edge(s4.w, d4.w, dinv, scales, off, cursor, csr);
    }
    if (i < (E & 3)) {
        int e = e4 * 4 + i;
        fill_edge(src[e], dst[e], dinv, scales, off, cursor, csr);
    }
}

// ---------------- fused aggregate + MFMA GEMM + bias + ReLU (r9 verbatim) ----
__global__ __launch_bounds__(256) void aggemm(
        const char* __restrict__ xq, const float* __restrict__ scales,
        const int* __restrict__ off, const int2* __restrict__ csr,
        const float* __restrict__ dinv,
        const float* __restrict__ W, const float* __restrict__ bias,
        int N, float* __restrict__ out) {
    __shared__ unsigned short Wt[128 * 128];   // [c][k] bf16, XOR-swizzled, 32 KB

    int t = threadIdx.x;
    {
        int c = t & 127;
        int khalf = t >> 7;
        #pragma unroll
        for (int kc = 0; kc < 8; kc++) {
            int k0 = khalf * 64 + kc * 8;
            unsigned int u0 = f2b_bits(W[(size_t)(k0 + 0) * 128 + c]) |
                             (f2b_bits(W[(size_t)(k0 + 1) * 128 + c]) << 16);
            unsigned int u1 = f2b_bits(W[(size_t)(k0 + 2) * 128 + c]) |
                             (f2b_bits(W[(size_t)(k0 + 3) * 128 + c]) << 16);
            unsigned int u2 = f2b_bits(W[(size_t)(k0 + 4) * 128 + c]) |
                             (f2b_bits(W[(size_t)(k0 + 5) * 128 + c]) << 16);
            unsigned int u3 = f2b_bits(W[(size_t)(k0 + 6) * 128 + c]) |
                             (f2b_bits(W[(size_t)(k0 + 7) * 128 + c]) << 16);
            int byte = c * 256 + k0 * 2;
            byte ^= (c & 7) << 4;
            *(uint4*)((char*)Wt + byte) = make_uint4(u0, u1, u2, u3);
        }
    }
    __syncthreads();

    int wid = t >> 6, lane = t & 63;
    int pair = blockIdx.x * 4 + wid;
    int n0 = pair * 2;
    if (n0 >= N) return;

    int rit = lane & 15;
    int g   = lane >> 4;
    int mynode = n0 + (rit >> 3);
    if (mynode >= N) mynode = n0;
    int kslice = rit & 7;

    int offA = off[n0];
    int offMid = off[n0 + 1];
    int offEnd = (n0 + 2 <= N) ? off[n0 + 2] : offMid;
    int degA = offMid - offA;
    int degB = (n0 + 1 < N) ? (offEnd - offMid) : 0;
    int maxd = max(degA, degB);
    int myoff = (rit < 8) ? offA : offMid;
    int mydeg = (rit < 8) ? degA : degB;

    const size_t rofs = (size_t)kslice * 128 + g * 32;

    float acc[32];
    #pragma unroll
    for (int i = 0; i < 32; i++) acc[i] = 0.f;

    float selfw;
    {
        float ds = dinv[mynode];
        selfw = ds * ds * scales[mynode];
    }

    for (int j = -1; j < maxd; j++) {
        int s;
        float wgt;
        if (j < 0) {
            s = mynode;
            wgt = selfw;
        } else if (j < mydeg) {
            int2 cc = csr[myoff + j];
            s = cc.x;
            wgt = __int_as_float(cc.y);
        } else {
            s = mynode;
            wgt = 0.f;
        }
        const uint4* rb = (const uint4*)(xq + (size_t)s * 1024 + rofs);
        uint4 q0 = rb[0];
        uint4 q1 = rb[1];
        #define UNPK(wrd, base)                                              \
            acc[(base) + 0] += (float)(signed char)((wrd)      )  * wgt;     \
            acc[(base) + 1] += (float)(signed char)((wrd) >>  8) * wgt;      \
            acc[(base) + 2] += (float)(signed char)((wrd) >> 16) * wgt;     \
            acc[(base) + 3] += (float)(signed char)((wrd) >> 24) * wgt;
        UNPK(q0.x, 0)  UNPK(q0.y, 4)  UNPK(q0.z, 8)  UNPK(q0.w, 12)
        UNPK(q1.x, 16) UNPK(q1.y, 20) UNPK(q1.z, 24) UNPK(q1.w, 28)
        #undef UNPK
    }

    bf16x8 afrag[4];
    #pragma unroll
    for (int kt = 0; kt < 4; kt++) {
        #pragma unroll
        for (int e = 0; e < 8; e++)
            afrag[kt][e] = (short)f2b_bits(acc[kt * 8 + e]);
    }

    long long r0 = (long long)n0 * 8;
    #pragma unroll
    for (int ct = 0; ct < 8; ct++) {
        int c = ct * 16 + rit;
        f32x4 acct = {0.f, 0.f, 0.f, 0.f};
        #pragma unroll
        for (int kt = 0; kt < 4; kt++) {
            int byte = c * 256 + kt * 64 + g * 16;
            byte ^= (c & 7) << 4;
            bf16x8 bfrag = *(const bf16x8*)((const char*)Wt + byte);
            acct = __builtin_amdgcn_mfma_f32_16x16x32_bf16(afrag[kt], bfrag, acct, 0, 0, 0);
        }
        float bv = bias[c];
        #pragma unroll
        for (int r = 0; r < 4; r++) {
            long long row = r0 + g * 4 + r;
            out[row * 128 + c] = fmaxf(acct[r] + bv, 0.f);
        }
    }
}

// ---------------- launch ----------------
extern "C" void kernel_launch(void* const* d_in, const int* in_sizes, int n_in,
                              void* d_out, int out_size, void* d_ws, size_t ws_size,
                              hipStream_t stream) {
    const float* x  = (const float*)d_in[0];
    const int*   ei = (const int*)d_in[1];
    const float* W  = (const float*)d_in[2];
    const float* b  = (const float*)d_in[3];
    float* out = (float*)d_out;

    int N = in_sizes[0] / (KSL * DIN);
    int E = in_sizes[1] / 2;
    const int* src = ei;
    const int* dst = ei + E;

    char* ws = (char*)d_ws;
    size_t o = 0;
    auto alloc = [&](size_t bytes) -> void* {
        o = (o + 255) & ~(size_t)255;
        void* p = ws + o;
        o += bytes;
        return p;
    };
    int*   deg       = (int*)alloc((size_t)N * 4);
    int*   cursor    = (int*)alloc((size_t)N * 4);   // adjacent to deg: one memset (fallback)
    int*   off       = (int*)alloc((size_t)(N + 1) * 4);
    float* dinv      = (float*)alloc((size_t)N * 4);
    float* scales    = (float*)alloc((size_t)N * 4);
    int*   blockSums = (int*)alloc((size_t)NB * 4);
    int2*  csr       = (int2*)alloc((size_t)(E + 1) * 8);
    char*  xq        = (char*)alloc((size_t)N * KSL * DIN);

    // ---- single cooperative prep dispatch (2 blocks/CU) ----
    {
        const float* xa = x; char* xqa = xq; float* sca = scales; int Na = N;
        const int* sra = src; const int* dsa = dst; int Ea = E;
        int* dega = deg; int* cura = cursor; int* offa = off;
        float* dva = dinv; int* bsa = blockSums; int2* csra = csr;
        void* args[] = {&xa, &xqa, &sca, &Na, &sra, &dsa, &Ea,
                        &dega, &cura, &offa, &dva, &bsa, &csra};
        hipError_t err = hipLaunchCooperativeKernel(
            reinterpret_cast<void*>(build_all), dim3(NB), dim3(NT), args, 0, stream);
        if (err != hipSuccess) {
            // fallback: r9's proven 4-dispatch chain
            size_t z_bytes = (size_t)((char*)cursor - (char*)deg) + (size_t)N * 4;
            hipMemsetAsync(deg, 0, z_bytes, stream);
            long long qthreads = (long long)N * 64;
            int qblocks = (int)((qthreads + 255) / 256);
            quant_deg_fb<<<qblocks, 256, 0, stream>>>(x, xq, scales, N, dst, E, deg);
            scan_off_fb<<<1, 1024, 0, stream>>>(deg, N, off, dinv);
            fill_csr_fb<<<((E >> 2) + 255) / 256, 256, 0, stream>>>(src, dst, E, off,
                                                                    cursor, dinv, scales, csr);
        }
    }

    int pairs = (N + 1) / 2;
    int blocks = (pairs + 3) / 4;
    aggemm<<<blocks, 256, 0, stream>>>(xq, scales, off, csr, dinv, W, b, N, out);
}

// Round 12
// 427.347 us; speedup vs baseline: 1.3925x; 1.3925x over previous
//
#include <hip/hip_runtime.h>

#define KSL 8
#define DIN 128
#define DOUT 128

typedef __attribute__((ext_vector_type(8))) short bf16x8;
typedef __attribute__((ext_vector_type(4))) float f32x4;

// round-to-nearest-even fp32 -> bf16 bits
static __device__ __forceinline__ unsigned int f2b_bits(float f) {
    unsigned int u = __float_as_uint(f);
    return (u + 0x7fffu + ((u >> 16) & 1u)) >> 16;
}

static __device__ __forceinline__ float amax8(float4 a0, float4 a1,
                                              float4 b0, float4 b1) {
    float m = fmaxf(fmaxf(fmaxf(fabsf(a0.x), fabsf(a0.y)), fmaxf(fabsf(a0.z), fabsf(a0.w))),
                    fmaxf(fmaxf(fabsf(a1.x), fabsf(a1.y)), fmaxf(fabsf(a1.z), fabsf(a1.w))));
    m = fmaxf(m, fmaxf(fmaxf(fmaxf(fabsf(b0.x), fabsf(b0.y)), fmaxf(fabsf(b0.z), fabsf(b0.w))),
                       fmaxf(fmaxf(fabsf(b1.x), fabsf(b1.y)), fmaxf(fabsf(b1.z), fabsf(b1.w)))));
    return m;
}

static __device__ __forceinline__ unsigned int pack4(float4 v, float inv) {
    int q0 = __float2int_rn(v.x * inv), q1 = __float2int_rn(v.y * inv);
    int q2 = __float2int_rn(v.z * inv), q3 = __float2int_rn(v.w * inv);
    return (q0 & 0xff) | ((q1 & 0xff) << 8) | ((q2 & 0xff) << 16) |
           ((unsigned)(q3 & 0xff) << 24);
}

// ---------------- quantize x -> permuted int8 + per-node scale; deg count ----
// One wave per node. Row layout (per (node,kslice), 128B): d' = g*32 + kt*8 + e
// stores element d = kt*32 + g*8 + e, so aggemm lane (rit,g) reads its 32
// fragment bytes CONTIGUOUSLY (2 x b128). (r9-proven)
__global__ __launch_bounds__(256) void quant_deg(
        const float* __restrict__ x, char* __restrict__ xq,
        float* __restrict__ scales, int N,
        const int* __restrict__ dst, int E, int* __restrict__ deg) {
    long long tid = (long long)blockIdx.x * blockDim.x + threadIdx.x;
    int e4 = E >> 2;
    if (tid < e4) {
        int4 d = ((const int4*)dst)[tid];
        atomicAdd(&deg[d.x], 1);
        atomicAdd(&deg[d.y], 1);
        atomicAdd(&deg[d.z], 1);
        atomicAdd(&deg[d.w], 1);
    }
    if (tid < (E & 3)) atomicAdd(&deg[dst[e4 * 4 + tid]], 1);

    int w = (int)(tid >> 6);
    int lane = (int)(tid & 63);
    if (w >= N) return;

    int ks = lane >> 3, chunk = lane & 7;
    int g = chunk >> 1, ktb = (chunk & 1) * 2;
    const float* p0 = x + (size_t)w * (KSL * DIN) + (size_t)ks * DIN + ktb * 32 + g * 8;
    float4 a0 = ((const float4*)p0)[0];
    float4 a1 = ((const float4*)p0)[1];
    float4 b0 = ((const float4*)(p0 + 32))[0];
    float4 b1 = ((const float4*)(p0 + 32))[1];
    float m = amax8(a0, a1, b0, b1);
    #pragma unroll
    for (int s = 32; s > 0; s >>= 1) m = fmaxf(m, __shfl_xor(m, s));

    float inv = (m > 0.f) ? 127.f / m : 0.f;
    uint4 o;
    o.x = pack4(a0, inv);
    o.y = pack4(a1, inv);
    o.z = pack4(b0, inv);
    o.w = pack4(b1, inv);
    *(uint4*)(xq + (size_t)w * 1024 + lane * 16) = o;
    if (lane == 0) scales[w] = m * (1.f / 127.f);
}

// ---------------- CSR offsets: serial chunks + one block scan ----------------
__global__ __launch_bounds__(1024) void scan_off_fast(const int* __restrict__ deg, int N,
                                                      int* __restrict__ off,
                                                      float* __restrict__ dinv) {
    __shared__ int part[1024];
    int tid = threadIdx.x;
    int CH = (N + 1023) / 1024;
    int i0 = tid * CH;
    int s = 0;
    for (int j = 0; j < CH; j++) {
        int i = i0 + j;
        if (i < N) {
            int d = deg[i];
            dinv[i] = rsqrtf((float)(d + 1));   // +1 self-loop
            s += d;
        }
    }
    part[tid] = s;
    __syncthreads();
    for (int st = 1; st < 1024; st <<= 1) {
        int t = (tid >= st) ? part[tid - st] : 0;
        __syncthreads();
        part[tid] += t;
        __syncthreads();
    }
    int run = part[tid] - s;   // exclusive prefix
    for (int j = 0; j < CH; j++) {
        int i = i0 + j;
        if (i < N) {
            off[i] = run;
            run += deg[i];
        }
    }
    if (tid == 1023) off[N] = part[1023];
}

// ---------------- CSR fill: int4 edge loads; scale folded into weight -------
static __device__ __forceinline__ void fill_edge(
        int s, int d, const float* __restrict__ dinv,
        const float* __restrict__ scales, const int* __restrict__ off,
        int* __restrict__ cursor, int2* __restrict__ csr) {
    int pos = atomicAdd(&cursor[d], 1);
    csr[off[d] + pos] = make_int2(s, __float_as_int(dinv[s] * dinv[d] * scales[s]));
}

__global__ __launch_bounds__(256) void fill_csr(
        const int* __restrict__ src, const int* __restrict__ dst, int E,
        const int* __restrict__ off, int* __restrict__ cursor,
        const float* __restrict__ dinv, const float* __restrict__ scales,
        int2* __restrict__ csr) {
    int i = blockIdx.x * blockDim.x + threadIdx.x;
    int e4 = E >> 2;
    if (i < e4) {
        int4 s4 = ((const int4*)src)[i];
        int4 d4 = ((const int4*)dst)[i];
        fill_edge(s4.x, d4.x, dinv, scales, off, cursor, csr);
        fill_edge(s4.y, d4.y, dinv, scales, off, cursor, csr);
        fill_edge(s4.z, d4.z, dinv, scales, off, cursor, csr);
        fill_edge(s4.w, d4.w, dinv, scales, off, cursor, csr);
    }
    if (i < (E & 3)) {
        int e = e4 * 4 + i;
        fill_edge(src[e], dst[e], dinv, scales, off, cursor, csr);
    }
}

// ---------------- fused aggregate + MFMA GEMM + bias + ReLU ----------------
// r9 structure; this round's single change: csr edge records are loaded via
// SCALAR loads (wave-uniform base offAu/offMu from readfirstlane, uniform j)
// -> s_load_dwordx2 on the SMEM path, freeing the VMEM TA. Per-iteration
// VMEM: 2 gather instrs = 128 lane-addrs (was 192). Numerics identical to r9.
__global__ __launch_bounds__(256) void aggemm(
        const char* __restrict__ xq, const float* __restrict__ scales,
        const int* __restrict__ off, const int2* __restrict__ csr,
        const float* __restrict__ dinv,
        const float* __restrict__ W, const float* __restrict__ bias,
        int N, float* __restrict__ out) {
    __shared__ unsigned short Wt[128 * 128];   // [c][k] bf16, XOR-swizzled, 32 KB

    int t = threadIdx.x;
    // ---- stage W^T as bf16 with XOR swizzle on byte bits 4..6 (r2-verified) ----
    {
        int c = t & 127;
        int khalf = t >> 7;
        #pragma unroll
        for (int kc = 0; kc < 8; kc++) {
            int k0 = khalf * 64 + kc * 8;
            unsigned int u0 = f2b_bits(W[(size_t)(k0 + 0) * 128 + c]) |
                             (f2b_bits(W[(size_t)(k0 + 1) * 128 + c]) << 16);
            unsigned int u1 = f2b_bits(W[(size_t)(k0 + 2) * 128 + c]) |
                             (f2b_bits(W[(size_t)(k0 + 3) * 128 + c]) << 16);
            unsigned int u2 = f2b_bits(W[(size_t)(k0 + 4) * 128 + c]) |
                             (f2b_bits(W[(size_t)(k0 + 5) * 128 + c]) << 16);
            unsigned int u3 = f2b_bits(W[(size_t)(k0 + 6) * 128 + c]) |
                             (f2b_bits(W[(size_t)(k0 + 7) * 128 + c]) << 16);
            int byte = c * 256 + k0 * 2;
            byte ^= (c & 7) << 4;
            *(uint4*)((char*)Wt + byte) = make_uint4(u0, u1, u2, u3);
        }
    }
    __syncthreads();

    int wid = t >> 6, lane = t & 63;
    int pair = blockIdx.x * 4 + wid;
    int n0 = pair * 2;
    if (n0 >= N) return;

    int rit = lane & 15;          // row in 16-row tile
    int g   = lane >> 4;          // k-group 0..3
    int mynode = n0 + (rit >> 3);
    if (mynode >= N) mynode = n0; // odd-N guard
    int kslice = rit & 7;

    // wave-uniform CSR bounds -> SGPRs (enables scalar loads in the loop)
    int offAu = __builtin_amdgcn_readfirstlane(off[n0]);
    int offMu = __builtin_amdgcn_readfirstlane(off[n0 + 1]);
    int offEu = __builtin_amdgcn_readfirstlane((n0 + 2 <= N) ? off[n0 + 2] : 0);
    int degAu = offMu - offAu;
    int degBu = (n0 + 1 < N) ? (offEu - offMu) : 0;
    int maxd  = max(degAu, degBu);
    int mydeg = (rit < 8) ? degAu : degBu;
    bool isA  = (rit < 8);
    const int2* csrA = csr + offAu;
    const int2* csrB = csr + offMu;

    const size_t rofs = (size_t)kslice * 128 + g * 32;  // lane's 32B in 1KB row

    float acc[32];

    // ---- self-loop term (hoisted; initializes acc) ----
    {
        float ds = dinv[mynode];
        float selfw = ds * ds * scales[mynode];
        const uint4* rb = (const uint4*)(xq + (size_t)mynode * 1024 + rofs);
        uint4 q0 = rb[0];
        uint4 q1 = rb[1];
        #define UNPK0(wrd, base)                                             \
            acc[(base) + 0] = (float)(signed char)((wrd)      )  * selfw;    \
            acc[(base) + 1] = (float)(signed char)((wrd) >>  8) * selfw;     \
            acc[(base) + 2] = (float)(signed char)((wrd) >> 16) * selfw;     \
            acc[(base) + 3] = (float)(signed char)((wrd) >> 24) * selfw;
        UNPK0(q0.x, 0)  UNPK0(q0.y, 4)  UNPK0(q0.z, 8)  UNPK0(q0.w, 12)
        UNPK0(q1.x, 16) UNPK0(q1.y, 20) UNPK0(q1.z, 24) UNPK0(q1.w, 28)
        #undef UNPK0
    }

    // ---- edge loop: scalar csr loads + 2 vector gathers ----
    for (int j = 0; j < maxd; j++) {
        int2 eA = csrA[j];          // uniform addr -> s_load_dwordx2
        int2 eB = csrB[j];          // uniform addr -> s_load_dwordx2
        bool valid = (j < mydeg);
        int   s   = isA ? eA.x : eB.x;
        float wgt = __int_as_float(isA ? eA.y : eB.y);
        s   = valid ? s : mynode;
        wgt = valid ? wgt : 0.f;

        const uint4* rb = (const uint4*)(xq + (size_t)s * 1024 + rofs);
        uint4 q0 = rb[0];
        uint4 q1 = rb[1];
        #define UNPK(wrd, base)                                              \
            acc[(base) + 0] += (float)(signed char)((wrd)      )  * wgt;     \
            acc[(base) + 1] += (float)(signed char)((wrd) >>  8) * wgt;      \
            acc[(base) + 2] += (float)(signed char)((wrd) >> 16) * wgt;      \
            acc[(base) + 3] += (float)(signed char)((wrd) >> 24) * wgt;
        UNPK(q0.x, 0)  UNPK(q0.y, 4)  UNPK(q0.z, 8)  UNPK(q0.w, 12)
        UNPK(q1.x, 16) UNPK(q1.y, 20) UNPK(q1.z, 24) UNPK(q1.w, 28)
        #undef UNPK
    }

    // pack accumulators -> A fragments (bf16); acc[kt*8+e] = d kt*32+g*8+e
    bf16x8 afrag[4];
    #pragma unroll
    for (int kt = 0; kt < 4; kt++) {
        #pragma unroll
        for (int e = 0; e < 8; e++)
            afrag[kt][e] = (short)f2b_bits(acc[kt * 8 + e]);
    }

    // GEMM: 8 column tiles of 16, K = 128 in 4 MFMAs each; B-frags from LDS
    long long r0 = (long long)n0 * 8;
    #pragma unroll
    for (int ct = 0; ct < 8; ct++) {
        int c = ct * 16 + rit;     // output column (C/D: col = lane&15)
        f32x4 acct = {0.f, 0.f, 0.f, 0.f};
        #pragma unroll
        for (int kt = 0; kt < 4; kt++) {
            int byte = c * 256 + kt * 64 + g * 16;
            byte ^= (c & 7) << 4;
            bf16x8 bfrag = *(const bf16x8*)((const char*)Wt + byte);
            acct = __builtin_amdgcn_mfma_f32_16x16x32_bf16(afrag[kt], bfrag, acct, 0, 0, 0);
        }
        float bv = bias[c];
        #pragma unroll
        for (int r = 0; r < 4; r++) {
            long long row = r0 + g * 4 + r;   // C/D: row = (lane>>4)*4 + reg
            out[row * 128 + c] = fmaxf(acct[r] + bv, 0.f);
        }
    }
}

// ---------------- launch ----------------
extern "C" void kernel_launch(void* const* d_in, const int* in_sizes, int n_in,
                              void* d_out, int out_size, void* d_ws, size_t ws_size,
                              hipStream_t stream) {
    const float* x  = (const float*)d_in[0];
    const int*   ei = (const int*)d_in[1];
    const float* W  = (const float*)d_in[2];
    const float* b  = (const float*)d_in[3];
    float* out = (float*)d_out;

    int N = in_sizes[0] / (KSL * DIN);
    int E = in_sizes[1] / 2;
    const int* src = ei;
    const int* dst = ei + E;

    char* ws = (char*)d_ws;
    size_t o = 0;
    auto alloc = [&](size_t bytes) -> void* {
        o = (o + 255) & ~(size_t)255;
        void* p = ws + o;
        o += bytes;
        return p;
    };
    int*   deg    = (int*)alloc((size_t)N * 4);
    int*   cursor = (int*)alloc((size_t)N * 4);     // adjacent to deg: one memset
    int*   off    = (int*)alloc((size_t)(N + 1) * 4);
    float* dinv   = (float*)alloc((size_t)N * 4);
    float* scales = (float*)alloc((size_t)N * 4);
    int2*  csr    = (int2*)alloc((size_t)(E + 1) * 8);
    char*  xq     = (char*)alloc((size_t)N * KSL * DIN);

    // one memset covers deg + alignment gap + cursor
    size_t z_bytes = (size_t)((char*)cursor - (char*)deg) + (size_t)N * 4;
    hipMemsetAsync(deg, 0, z_bytes, stream);

    long long qthreads = (long long)N * 64;
    int qblocks = (int)((qthreads + 255) / 256);
    quant_deg<<<qblocks, 256, 0, stream>>>(x, xq, scales, N, dst, E, deg);
    scan_off_fast<<<1, 1024, 0, stream>>>(deg, N, off, dinv);
    fill_csr<<<((E >> 2) + 255) / 256, 256, 0, stream>>>(src, dst, E, off, cursor,
                                                         dinv, scales, csr);

    int pairs = (N + 1) / 2;
    int blocks = (pairs + 3) / 4;
    aggemm<<<blocks, 256, 0, stream>>>(xq, scales, off, csr, dinv, W, b, N, out);
}

// Round 13
// 304.440 us; speedup vs baseline: 1.9546x; 1.4037x over previous
//
#include <hip/hip_runtime.h>

#define KSL 8
#define DIN 128
#define DOUT 128

typedef __attribute__((ext_vector_type(8))) short bf16x8;
typedef __attribute__((ext_vector_type(4))) float f32x4;

// round-to-nearest-even fp32 -> bf16 bits
static __device__ __forceinline__ unsigned int f2b_bits(float f) {
    unsigned int u = __float_as_uint(f);
    return (u + 0x7fffu + ((u >> 16) & 1u)) >> 16;
}

static __device__ __forceinline__ float amax8(float4 a0, float4 a1,
                                              float4 b0, float4 b1) {
    float m = fmaxf(fmaxf(fmaxf(fabsf(a0.x), fabsf(a0.y)), fmaxf(fabsf(a0.z), fabsf(a0.w))),
                    fmaxf(fmaxf(fabsf(a1.x), fabsf(a1.y)), fmaxf(fabsf(a1.z), fabsf(a1.w))));
    m = fmaxf(m, fmaxf(fmaxf(fmaxf(fabsf(b0.x), fabsf(b0.y)), fmaxf(fabsf(b0.z), fabsf(b0.w))),
                       fmaxf(fmaxf(fabsf(b1.x), fabsf(b1.y)), fmaxf(fabsf(b1.z), fabsf(b1.w)))));
    return m;
}

static __device__ __forceinline__ unsigned int pack4(float4 v, float inv) {
    int q0 = __float2int_rn(v.x * inv), q1 = __float2int_rn(v.y * inv);
    int q2 = __float2int_rn(v.z * inv), q3 = __float2int_rn(v.w * inv);
    return (q0 & 0xff) | ((q1 & 0xff) << 8) | ((q2 & 0xff) << 16) |
           ((unsigned)(q3 & 0xff) << 24);
}

// ---------------- quantize x -> permuted int8 + per-node scale; deg count ----
// (r9/r12-proven, verbatim)
__global__ __launch_bounds__(256) void quant_deg(
        const float* __restrict__ x, char* __restrict__ xq,
        float* __restrict__ scales, int N,
        const int* __restrict__ dst, int E, int* __restrict__ deg) {
    long long tid = (long long)blockIdx.x * blockDim.x + threadIdx.x;
    int e4 = E >> 2;
    if (tid < e4) {
        int4 d = ((const int4*)dst)[tid];
        atomicAdd(&deg[d.x], 1);
        atomicAdd(&deg[d.y], 1);
        atomicAdd(&deg[d.z], 1);
        atomicAdd(&deg[d.w], 1);
    }
    if (tid < (E & 3)) atomicAdd(&deg[dst[e4 * 4 + tid]], 1);

    int w = (int)(tid >> 6);
    int lane = (int)(tid & 63);
    if (w >= N) return;

    int ks = lane >> 3, chunk = lane & 7;
    int g = chunk >> 1, ktb = (chunk & 1) * 2;
    const float* p0 = x + (size_t)w * (KSL * DIN) + (size_t)ks * DIN + ktb * 32 + g * 8;
    float4 a0 = ((const float4*)p0)[0];
    float4 a1 = ((const float4*)p0)[1];
    float4 b0 = ((const float4*)(p0 + 32))[0];
    float4 b1 = ((const float4*)(p0 + 32))[1];
    float m = amax8(a0, a1, b0, b1);
    #pragma unroll
    for (int s = 32; s > 0; s >>= 1) m = fmaxf(m, __shfl_xor(m, s));

    float inv = (m > 0.f) ? 127.f / m : 0.f;
    uint4 o;
    o.x = pack4(a0, inv);
    o.y = pack4(a1, inv);
    o.z = pack4(b0, inv);
    o.w = pack4(b1, inv);
    *(uint4*)(xq + (size_t)w * 1024 + lane * 16) = o;
    if (lane == 0) scales[w] = m * (1.f / 127.f);
}

// ---------------- parallel scan, stage 1: per-block chunk sums + dinv + sd ---
__global__ __launch_bounds__(256) void partial_sums(
        const int* __restrict__ deg, int N, int CHK,
        const float* __restrict__ scales,
        float* __restrict__ dinv, float* __restrict__ sd,
        int* __restrict__ blockSums) {
    __shared__ int red[256];
    int b = blockIdx.x, t = threadIdx.x;
    int start = b * CHK;
    int end = min(start + CHK, N);
    int s = 0;
    for (int i = start + t; i < end; i += 256) {
        int d = deg[i];
        float di = rsqrtf((float)(d + 1));   // +1 self-loop
        dinv[i] = di;
        sd[i] = di * scales[i];
        s += d;
    }
    red[t] = s;
    __syncthreads();
    #pragma unroll
    for (int st = 128; st > 0; st >>= 1) {
        if (t < st) red[t] += red[t + st];
        __syncthreads();
    }
    if (t == 0) blockSums[b] = red[0];
}

// ---------------- stage 2: one tiny block scans the 256 partials -------------
__global__ __launch_bounds__(256) void scan_bases(
        int* __restrict__ blockSums, int nb, int* __restrict__ off, int N) {
    __shared__ int buf[256];
    int t = threadIdx.x;
    int v = (t < nb) ? blockSums[t] : 0;
    buf[t] = v;
    __syncthreads();
    #pragma unroll
    for (int st = 1; st < 256; st <<= 1) {
        int u = (t >= st) ? buf[t - st] : 0;
        __syncthreads();
        buf[t] += u;
        __syncthreads();
    }
    if (t < nb) blockSums[t] = buf[t] - v;   // exclusive base per block
    if (t == 255) off[N] = buf[255];         // grand total
}

// ---------------- stage 3: per-block LDS scan of its chunk -> off ------------
__global__ __launch_bounds__(256) void write_off(
        const int* __restrict__ deg, int N, int CHK,
        const int* __restrict__ blockSums, int* __restrict__ off) {
    __shared__ int buf[256];
    int b = blockIdx.x, t = threadIdx.x;
    int start = b * CHK;
    int end = min(start + CHK, N);
    int run = blockSums[b];
    for (int base = start; base < end; base += 256) {
        int i = base + t;
        int d = (i < end) ? deg[i] : 0;
        __syncthreads();                     // protect prev-iter buf reads
        buf[t] = d;
        __syncthreads();
        #pragma unroll
        for (int st = 1; st < 256; st <<= 1) {
            int u = (t >= st) ? buf[t - st] : 0;
            __syncthreads();
            buf[t] += u;
            __syncthreads();
        }
        if (i < end) off[i] = run + buf[t] - d;   // exclusive prefix
        run += buf[255];                          // chunk-tile total (uniform)
    }
}

// ---------------- CSR fill: int4 edge loads; weight = sd[s] * dinv[d] -------
static __device__ __forceinline__ void fill_edge(
        int s, int d, const float* __restrict__ dinv,
        const float* __restrict__ sd, const int* __restrict__ off,
        int* __restrict__ cursor, int2* __restrict__ csr) {
    int pos = atomicAdd(&cursor[d], 1);
    csr[off[d] + pos] = make_int2(s, __float_as_int(sd[s] * dinv[d]));
}

__global__ __launch_bounds__(256) void fill_csr(
        const int* __restrict__ src, const int* __restrict__ dst, int E,
        const int* __restrict__ off, int* __restrict__ cursor,
        const float* __restrict__ dinv, const float* __restrict__ sd,
        int2* __restrict__ csr) {
    int i = blockIdx.x * blockDim.x + threadIdx.x;
    int e4 = E >> 2;
    if (i < e4) {
        int4 s4 = ((const int4*)src)[i];
        int4 d4 = ((const int4*)dst)[i];
        fill_edge(s4.x, d4.x, dinv, sd, off, cursor, csr);
        fill_edge(s4.y, d4.y, dinv, sd, off, cursor, csr);
        fill_edge(s4.z, d4.z, dinv, sd, off, cursor, csr);
        fill_edge(s4.w, d4.w, dinv, sd, off, cursor, csr);
    }
    if (i < (E & 3)) {
        int e = e4 * 4 + i;
        fill_edge(src[e], dst[e], dinv, sd, off, cursor, csr);
    }
}

// ---------------- fused aggregate + MFMA GEMM + bias + ReLU (r12 verbatim) ---
__global__ __launch_bounds__(256) void aggemm(
        const char* __restrict__ xq, const float* __restrict__ scales,
        const int* __restrict__ off, const int2* __restrict__ csr,
        const float* __restrict__ dinv,
        const float* __restrict__ W, const float* __restrict__ bias,
        int N, float* __restrict__ out) {
    __shared__ unsigned short Wt[128 * 128];   // [c][k] bf16, XOR-swizzled, 32 KB

    int t = threadIdx.x;
    {
        int c = t & 127;
        int khalf = t >> 7;
        #pragma unroll
        for (int kc = 0; kc < 8; kc++) {
            int k0 = khalf * 64 + kc * 8;
            unsigned int u0 = f2b_bits(W[(size_t)(k0 + 0) * 128 + c]) |
                             (f2b_bits(W[(size_t)(k0 + 1) * 128 + c]) << 16);
            unsigned int u1 = f2b_bits(W[(size_t)(k0 + 2) * 128 + c]) |
                             (f2b_bits(W[(size_t)(k0 + 3) * 128 + c]) << 16);
            unsigned int u2 = f2b_bits(W[(size_t)(k0 + 4) * 128 + c]) |
                             (f2b_bits(W[(size_t)(k0 + 5) * 128 + c]) << 16);
            unsigned int u3 = f2b_bits(W[(size_t)(k0 + 6) * 128 + c]) |
                             (f2b_bits(W[(size_t)(k0 + 7) * 128 + c]) << 16);
            int byte = c * 256 + k0 * 2;
            byte ^= (c & 7) << 4;
            *(uint4*)((char*)Wt + byte) = make_uint4(u0, u1, u2, u3);
        }
    }
    __syncthreads();

    int wid = t >> 6, lane = t & 63;
    int pair = blockIdx.x * 4 + wid;
    int n0 = pair * 2;
    if (n0 >= N) return;

    int rit = lane & 15;          // row in 16-row tile
    int g   = lane >> 4;          // k-group 0..3
    int mynode = n0 + (rit >> 3);
    if (mynode >= N) mynode = n0; // odd-N guard
    int kslice = rit & 7;

    // wave-uniform CSR bounds -> SGPRs (enables scalar loads in the loop)
    int offAu = __builtin_amdgcn_readfirstlane(off[n0]);
    int offMu = __builtin_amdgcn_readfirstlane(off[n0 + 1]);
    int offEu = __builtin_amdgcn_readfirstlane((n0 + 2 <= N) ? off[n0 + 2] : 0);
    int degAu = offMu - offAu;
    int degBu = (n0 + 1 < N) ? (offEu - offMu) : 0;
    int maxd  = max(degAu, degBu);
    int mydeg = (rit < 8) ? degAu : degBu;
    bool isA  = (rit < 8);
    const int2* csrA = csr + offAu;
    const int2* csrB = csr + offMu;

    const size_t rofs = (size_t)kslice * 128 + g * 32;  // lane's 32B in 1KB row

    float acc[32];

    // ---- self-loop term (hoisted; initializes acc) ----
    {
        float ds = dinv[mynode];
        float selfw = ds * ds * scales[mynode];
        const uint4* rb = (const uint4*)(xq + (size_t)mynode * 1024 + rofs);
        uint4 q0 = rb[0];
        uint4 q1 = rb[1];
        #define UNPK0(wrd, base)                                             \
            acc[(base) + 0] = (float)(signed char)((wrd)      )  * selfw;    \
            acc[(base) + 1] = (float)(signed char)((wrd) >>  8) * selfw;     \
            acc[(base) + 2] = (float)(signed char)((wrd) >> 16) * selfw;     \
            acc[(base) + 3] = (float)(signed char)((wrd) >> 24) * selfw;
        UNPK0(q0.x, 0)  UNPK0(q0.y, 4)  UNPK0(q0.z, 8)  UNPK0(q0.w, 12)
        UNPK0(q1.x, 16) UNPK0(q1.y, 20) UNPK0(q1.z, 24) UNPK0(q1.w, 28)
        #undef UNPK0
    }

    // ---- edge loop: scalar csr loads + 2 vector gathers ----
    for (int j = 0; j < maxd; j++) {
        int2 eA = csrA[j];          // uniform addr -> s_load_dwordx2
        int2 eB = csrB[j];          // uniform addr -> s_load_dwordx2
        bool valid = (j < mydeg);
        int   s   = isA ? eA.x : eB.x;
        float wgt = __int_as_float(isA ? eA.y : eB.y);
        s   = valid ? s : mynode;
        wgt = valid ? wgt : 0.f;

        const uint4* rb = (const uint4*)(xq + (size_t)s * 1024 + rofs);
        uint4 q0 = rb[0];
        uint4 q1 = rb[1];
        #define UNPK(wrd, base)                                              \
            acc[(base) + 0] += (float)(signed char)((wrd)      )  * wgt;     \
            acc[(base) + 1] += (float)(signed char)((wrd) >>  8) * wgt;      \
            acc[(base) + 2] += (float)(signed char)((wrd) >> 16) * wgt;      \
            acc[(base) + 3] += (float)(signed char)((wrd) >> 24) * wgt;
        UNPK(q0.x, 0)  UNPK(q0.y, 4)  UNPK(q0.z, 8)  UNPK(q0.w, 12)
        UNPK(q1.x, 16) UNPK(q1.y, 20) UNPK(q1.z, 24) UNPK(q1.w, 28)
        #undef UNPK
    }

    // pack accumulators -> A fragments (bf16); acc[kt*8+e] = d kt*32+g*8+e
    bf16x8 afrag[4];
    #pragma unroll
    for (int kt = 0; kt < 4; kt++) {
        #pragma unroll
        for (int e = 0; e < 8; e++)
            afrag[kt][e] = (short)f2b_bits(acc[kt * 8 + e]);
    }

    // GEMM: 8 column tiles of 16, K = 128 in 4 MFMAs each; B-frags from LDS
    long long r0 = (long long)n0 * 8;
    #pragma unroll
    for (int ct = 0; ct < 8; ct++) {
        int c = ct * 16 + rit;     // output column (C/D: col = lane&15)
        f32x4 acct = {0.f, 0.f, 0.f, 0.f};
        #pragma unroll
        for (int kt = 0; kt < 4; kt++) {
            int byte = c * 256 + kt * 64 + g * 16;
            byte ^= (c & 7) << 4;
            bf16x8 bfrag = *(const bf16x8*)((const char*)Wt + byte);
            acct = __builtin_amdgcn_mfma_f32_16x16x32_bf16(afrag[kt], bfrag, acct, 0, 0, 0);
        }
        float bv = bias[c];
        #pragma unroll
        for (int r = 0; r < 4; r++) {
            long long row = r0 + g * 4 + r;   // C/D: row = (lane>>4)*4 + reg
            out[row * 128 + c] = fmaxf(acct[r] + bv, 0.f);
        }
    }
}

// ---------------- launch ----------------
extern "C" void kernel_launch(void* const* d_in, const int* in_sizes, int n_in,
                              void* d_out, int out_size, void* d_ws, size_t ws_size,
                              hipStream_t stream) {
    const float* x  = (const float*)d_in[0];
    const int*   ei = (const int*)d_in[1];
    const float* W  = (const float*)d_in[2];
    const float* b  = (const float*)d_in[3];
    float* out = (float*)d_out;

    int N = in_sizes[0] / (KSL * DIN);
    int E = in_sizes[1] / 2;
    const int* src = ei;
    const int* dst = ei + E;

    char* ws = (char*)d_ws;
    size_t o = 0;
    auto alloc = [&](size_t bytes) -> void* {
        o = (o + 255) & ~(size_t)255;
        void* p = ws + o;
        o += bytes;
        return p;
    };
    int*   deg       = (int*)alloc((size_t)N * 4);
    int*   cursor    = (int*)alloc((size_t)N * 4);   // adjacent to deg: one memset
    int*   off       = (int*)alloc((size_t)(N + 1) * 4);
    float* dinv      = (float*)alloc((size_t)N * 4);
    float* scales    = (float*)alloc((size_t)N * 4);
    float* sd        = (float*)alloc((size_t)N * 4);
    int*   blockSums = (int*)alloc((size_t)256 * 4);
    int2*  csr       = (int2*)alloc((size_t)(E + 1) * 8);
    char*  xq        = (char*)alloc((size_t)N * KSL * DIN);

    // one memset covers deg + alignment gap + cursor
    size_t z_bytes = (size_t)((char*)cursor - (char*)deg) + (size_t)N * 4;
    hipMemsetAsync(deg, 0, z_bytes, stream);

    long long qthreads = (long long)N * 64;
    int qblocks = (int)((qthreads + 255) / 256);
    quant_deg<<<qblocks, 256, 0, stream>>>(x, xq, scales, N, dst, E, deg);

    int CHK = (N + 255) / 256;
    partial_sums<<<256, 256, 0, stream>>>(deg, N, CHK, scales, dinv, sd, blockSums);
    scan_bases<<<1, 256, 0, stream>>>(blockSums, 256, off, N);
    write_off<<<256, 256, 0, stream>>>(deg, N, CHK, blockSums, off);
    fill_csr<<<((E >> 2) + 255) / 256, 256, 0, stream>>>(src, dst, E, off, cursor,
                                                         dinv, sd, csr);

    int pairs = (N + 1) / 2;
    int blocks = (pairs + 3) / 4;
    aggemm<<<blocks, 256, 0, stream>>>(xq, scales, off, csr, dinv, W, b, N, out);
}